// Round 6
// baseline (280.929 us; speedup 1.0000x reference)
//
#include <hip/hip_runtime.h>
#include <math.h>
#include <stdint.h>

#define TOKN 23040
#define BSZ 64
#define SEQ 360
#define DIM 256
#define NHD 8
#define HDD 32
#define MLPD 1024
#define NEGV -1e9f

typedef __attribute__((ext_vector_type(8))) short bf16x8;
typedef __attribute__((ext_vector_type(4))) float f32x4;

static __device__ __forceinline__ short f2bs(float f) {
  unsigned u = __builtin_bit_cast(unsigned, f);
  u += 0x7fffu + ((u >> 16) & 1u);
  return (short)(u >> 16);
}
static __device__ __forceinline__ float bf2f(short s) {
  unsigned u = ((unsigned)(unsigned short)s) << 16;
  return __builtin_bit_cast(float, u);
}
static __device__ __forceinline__ unsigned packbf(float a, float b) {
  return (unsigned)(unsigned short)f2bs(a) | ((unsigned)(unsigned short)f2bs(b) << 16);
}
// async global->LDS, 16B/lane; LDS dest = wave-uniform base + lane*16
static __device__ __forceinline__ void gl16(const short* g, short* l) {
  __builtin_amdgcn_global_load_lds(
      (const __attribute__((address_space(1))) unsigned int*)g,
      (__attribute__((address_space(3))) unsigned int*)l, 16, 0, 0);
}

// ---------------- weight convert + transpose to bf16 [N][K] ----------------
__global__ __launch_bounds__(256) void convw_k(
    const float* __restrict__ wqkv, const float* __restrict__ wo,
    const float* __restrict__ w1, const float* __restrict__ w2,
    short* __restrict__ wqkvt, short* __restrict__ wot,
    short* __restrict__ w1t, short* __restrict__ w2t) {
  int id = blockIdx.x * 256 + threadIdx.x;
  if (id < 256 * 768) {
    int k = id / 768, n = id % 768;
    wqkvt[n * 256 + k] = f2bs(wqkv[id]);
  }
  if (id < 256 * 256) {
    int k = id >> 8, n = id & 255;
    wot[n * 256 + k] = f2bs(wo[id]);
  }
  if (id < 256 * 1024) {
    int k = id >> 10, n = id & 1023;
    w1t[n * 256 + k] = f2bs(w1[id]);
  }
  if (id < 1024 * 256) {
    int k = id >> 8, n = id & 255;
    w2t[n * 1024 + k] = f2bs(w2[id]);
  }
}

// ---------------- LN1 + router weight dot; 4 tokens/block ----------------
__global__ __launch_bounds__(256) void ln_router_k(
    const float* __restrict__ in, const float* __restrict__ g,
    const float* __restrict__ b, const float* __restrict__ wpw,
    const float* __restrict__ wpb, short* __restrict__ outn,
    float* __restrict__ wout, float* __restrict__ outx) {
  int tok = blockIdx.x * 4 + (threadIdx.x >> 6);
  int lane = threadIdx.x & 63;
  const float4 xv = *(const float4*)(in + (size_t)tok * DIM + lane * 4);
  *(float4*)(outx + (size_t)tok * DIM + lane * 4) = xv;  // passthrough default
  float s = xv.x + xv.y + xv.z + xv.w;
  float s2 = xv.x * xv.x + xv.y * xv.y + xv.z * xv.z + xv.w * xv.w;
#pragma unroll
  for (int o = 1; o < 64; o <<= 1) { s += __shfl_xor(s, o); s2 += __shfl_xor(s2, o); }
  float m = s * (1.f / DIM);
  float var = fmaxf(s2 * (1.f / DIM) - m * m, 0.f);
  float rstd = rsqrtf(var + 1e-5f);
  float4 gv = *(const float4*)(g + lane * 4);
  float4 bv = *(const float4*)(b + lane * 4);
  uint2 pk;
  pk.x = packbf((xv.x - m) * rstd * gv.x + bv.x, (xv.y - m) * rstd * gv.y + bv.y);
  pk.y = packbf((xv.z - m) * rstd * gv.z + bv.z, (xv.w - m) * rstd * gv.w + bv.w);
  *(uint2*)(outn + (size_t)tok * DIM + lane * 4) = pk;
  float4 wv = *(const float4*)(wpw + lane * 4);
  float wd = xv.x * wv.x + xv.y * wv.y + xv.z * wv.z + xv.w * wv.w;
#pragma unroll
  for (int o = 1; o < 64; o <<= 1) wd += __shfl_xor(wd, o);
  if (lane == 0) wout[tok] = wd + wpb[0];
}

// ---------------- LN2 compact; bf16 in -> bf16 out, wave early-exit ----------------
__global__ __launch_bounds__(256) void ln_k(
    const short* __restrict__ in, const float* __restrict__ g,
    const float* __restrict__ b, const int* __restrict__ mtotp,
    short* __restrict__ outn) {
  int tok = blockIdx.x * 4 + (threadIdx.x >> 6);
  int lane = threadIdx.x & 63;
  if (tok >= *mtotp) return;  // wave-uniform, no barriers in kernel
  union { uint2 v; short s[4]; } u;
  u.v = *(const uint2*)(in + (size_t)tok * DIM + lane * 4);
  float x0 = bf2f(u.s[0]), x1 = bf2f(u.s[1]), x2 = bf2f(u.s[2]), x3 = bf2f(u.s[3]);
  float s = x0 + x1 + x2 + x3;
  float s2 = x0 * x0 + x1 * x1 + x2 * x2 + x3 * x3;
#pragma unroll
  for (int o = 1; o < 64; o <<= 1) { s += __shfl_xor(s, o); s2 += __shfl_xor(s2, o); }
  float m = s * (1.f / DIM);
  float var = fmaxf(s2 * (1.f / DIM) - m * m, 0.f);
  float rstd = rsqrtf(var + 1e-5f);
  float4 gv = *(const float4*)(g + lane * 4);
  float4 bv = *(const float4*)(b + lane * 4);
  uint2 pk;
  pk.x = packbf((x0 - m) * rstd * gv.x + bv.x, (x1 - m) * rstd * gv.y + bv.y);
  pk.y = packbf((x2 - m) * rstd * gv.z + bv.z, (x3 - m) * rstd * gv.w + bv.w);
  *(uint2*)(outn + (size_t)tok * DIM + lane * 4) = pk;
}

// ---------------- router fused: a1 GEMM (fp32) + silu + a2 + argmax -> sel ----------------
__global__ __launch_bounds__(256) void router_gemm_k(
    const float* __restrict__ x, const float* __restrict__ a1w,
    const float* __restrict__ a1b, const float* __restrict__ a2w,
    const float* __restrict__ a2b, int* __restrict__ sel) {
  __shared__ __align__(16) float XT[32][65];
  __shared__ __align__(16) float WT[32][128];
  int m0 = blockIdx.x * 64;
  int t = threadIdx.x;
  int tx = t & 31, ty = t >> 5;
  float acc[8][4] = {};
  int r = t >> 2, c = (t & 3) * 8;
  int n2 = t >> 1, c2 = (t & 1) * 16;
  for (int k0 = 0; k0 < 256; k0 += 32) {
    float4 xa = *(const float4*)(x + (size_t)(m0 + r) * 256 + k0 + c);
    float4 xb = *(const float4*)(x + (size_t)(m0 + r) * 256 + k0 + c + 4);
    XT[c + 0][r] = xa.x; XT[c + 1][r] = xa.y; XT[c + 2][r] = xa.z; XT[c + 3][r] = xa.w;
    XT[c + 4][r] = xb.x; XT[c + 5][r] = xb.y; XT[c + 6][r] = xb.z; XT[c + 7][r] = xb.w;
#pragma unroll
    for (int j = 0; j < 4; j++) {
      float4 wv = *(const float4*)(a1w + (size_t)n2 * 256 + k0 + c2 + j * 4);
      WT[c2 + j * 4 + 0][n2] = wv.x;
      WT[c2 + j * 4 + 1][n2] = wv.y;
      WT[c2 + j * 4 + 2][n2] = wv.z;
      WT[c2 + j * 4 + 3][n2] = wv.w;
    }
    __syncthreads();
#pragma unroll 8
    for (int kk = 0; kk < 32; kk++) {
      float4 wv4 = *(const float4*)&WT[kk][tx * 4];
      float4 x0 = *(const float4*)&XT[kk][ty * 8];
      float4 x1 = *(const float4*)&XT[kk][ty * 8 + 4];
      float xr[8] = {x0.x, x0.y, x0.z, x0.w, x1.x, x1.y, x1.z, x1.w};
      float wr[4] = {wv4.x, wv4.y, wv4.z, wv4.w};
#pragma unroll
      for (int i = 0; i < 8; i++)
#pragma unroll
        for (int j = 0; j < 4; j++) acc[i][j] += xr[i] * wr[j];
    }
    __syncthreads();
  }
  float b1v[4], a20[4], a21[4];
#pragma unroll
  for (int j = 0; j < 4; j++) {
    int dim = tx * 4 + j;
    b1v[j] = a1b[dim];
    a20[j] = a2w[dim];
    a21[j] = a2w[128 + dim];
  }
  float bias0 = a2b[0], bias1 = a2b[1];
#pragma unroll
  for (int i = 0; i < 8; i++) {
    float l0 = 0.f, l1 = 0.f;
#pragma unroll
    for (int j = 0; j < 4; j++) {
      float v = acc[i][j] + b1v[j];
      float h = v / (1.f + expf(-v));
      l0 += h * a20[j];
      l1 += h * a21[j];
    }
#pragma unroll
    for (int o = 1; o < 32; o <<= 1) { l0 += __shfl_xor(l0, o); l1 += __shfl_xor(l1, o); }
    if (tx == 0) sel[m0 + ty * 8 + i] = (l1 + bias1 > l0 + bias0) ? 1 : 0;
  }
}

// ---------------- compaction ----------------
__global__ __launch_bounds__(512) void scanA_k(const int* __restrict__ sel,
                                               int* __restrict__ idxl,
                                               int* __restrict__ cnt) {
  __shared__ int sc[512];
  int b = blockIdx.x, t = threadIdx.x;
  int flag = (t < SEQ) ? sel[b * SEQ + t] : 0;
  sc[t] = flag;
  __syncthreads();
  int val = flag;
  for (int off = 1; off < 512; off <<= 1) {
    int add = (t >= off) ? sc[t - off] : 0;
    __syncthreads();
    val += add;
    sc[t] = val;
    __syncthreads();
  }
  if (flag) idxl[b * SEQ + (val - 1)] = t;
  if (t == 511) cnt[b] = val;
}

__global__ __launch_bounds__(512) void scanB_k(const int* __restrict__ cnt,
                                               int* __restrict__ startp,
                                               int* __restrict__ mtotp,
                                               int* __restrict__ g_idx,
                                               float* __restrict__ outavg) {
  __shared__ int sc[64];
  __shared__ int mt;
  int t = threadIdx.x;
  if (t < 64) sc[t] = cnt[t];
  __syncthreads();
  if (t == 0) {
    int run = 0;
    for (int b = 0; b < 64; b++) { startp[b] = run; run += sc[b]; }
    *mtotp = run;
    mt = run;
    outavg[0] = (float)run / 64.0f;  // avg_selected fused
  }
  __syncthreads();
  int m = mt;
  for (int i = m + t; i < TOKN; i += 512) g_idx[i] = 0;  // pad rows -> token 0
}

__global__ __launch_bounds__(512) void scanC_k(const int* __restrict__ idxl,
                                               const int* __restrict__ startp,
                                               const int* __restrict__ cnt,
                                               int* __restrict__ g_idx) {
  int b = blockIdx.x, t = threadIdx.x;
  int c = cnt[b], s0 = startp[b];
  for (int j = t; j < c; j += 512) g_idx[s0 + j] = b * SEQ + idxl[b * SEQ + j];
}

// ---------------- bf16 MFMA GEMM, m97-style 128x128 tile, BK=32 ----------------
// global_load_lds width-16 staging (4 issues/iter), 4 waves x (4x4) 16x16x32
// MFMAs = 16 MFMA + 8 ds_read_b128 per wave per barrier pair.
// MODE 0: A gathered via g_idx; outb = bf16(v)                     (qkv)
// MODE 1: outb = bf16(v + resf[g_idx[row]])                        (h1, bf16)
// MODE 2: outb = bf16(gelu(v))                                     (mlp act)
// MODE 3: out[g_idx[row]] = (v + bf2f(resb[row]))*wgt[g_idx[row]]  (scatter)
template <int MODE>
__global__ __launch_bounds__(256) void gemm_bt_k(
    const short* __restrict__ A, const short* __restrict__ Bt,
    const float* __restrict__ bias, const float* __restrict__ resf,
    const short* __restrict__ resb, const float* __restrict__ wgt,
    const int* __restrict__ g_idx, const int* __restrict__ mtotp,
    short* __restrict__ outb, float* __restrict__ outf, int Ndim, int Kdim) {
  int Mt = *mtotp;
  int m0 = blockIdx.y * 128;
  if (m0 >= Mt) return;
  __shared__ __align__(16) short As[128 * 32];
  __shared__ __align__(16) short Bs[128 * 32];
  int n0 = blockIdx.x * 128;
  int t = threadIdx.x;
  int wave = t >> 6, lane = t & 63;
  int l15 = lane & 15, quad = lane >> 4;
  int wr = (wave >> 1) * 64, wc = (wave & 1) * 64;
  // staging: unit u = issue*256 + t; row = u>>2, colgroup = (u&3)*8
  int r0 = t >> 2, c0 = (t & 3) * 8;
  long ar0 = (MODE == 0) ? g_idx[m0 + r0] : (m0 + r0);
  long ar1 = (MODE == 0) ? g_idx[m0 + r0 + 64] : (m0 + r0 + 64);
  const short* gA0 = A + ar0 * Kdim + c0;
  const short* gA1 = A + ar1 * Kdim + c0;
  const short* gB0 = Bt + (size_t)(n0 + r0) * Kdim + c0;
  const short* gB1 = Bt + (size_t)(n0 + r0 + 64) * Kdim + c0;
  short* lA = As + wave * 512;  // wave-uniform base; HW adds lane*16B
  short* lB = Bs + wave * 512;

  f32x4 acc[4][4];
#pragma unroll
  for (int i = 0; i < 4; i++)
#pragma unroll
    for (int j = 0; j < 4; j++)
#pragma unroll
      for (int r = 0; r < 4; r++) acc[i][j][r] = 0.f;

  for (int k0 = 0; k0 < Kdim; k0 += 32) {
    gl16(gA0 + k0, lA);
    gl16(gA1 + k0, lA + 2048);
    gl16(gB0 + k0, lB);
    gl16(gB1 + k0, lB + 2048);
    __syncthreads();
    bf16x8 af[4], bfr[4];
#pragma unroll
    for (int i = 0; i < 4; i++)
      af[i] = *(const bf16x8*)&As[(wr + i * 16 + l15) * 32 + quad * 8];
#pragma unroll
    for (int j = 0; j < 4; j++)
      bfr[j] = *(const bf16x8*)&Bs[(wc + j * 16 + l15) * 32 + quad * 8];
#pragma unroll
    for (int i = 0; i < 4; i++)
#pragma unroll
      for (int j = 0; j < 4; j++)
        acc[i][j] = __builtin_amdgcn_mfma_f32_16x16x32_bf16(af[i], bfr[j],
                                                            acc[i][j], 0, 0, 0);
    __syncthreads();
  }

#pragma unroll
  for (int i = 0; i < 4; i++) {
#pragma unroll
    for (int j = 0; j < 4; j++) {
      int col = n0 + wc + j * 16 + l15;
      float bcol = bias[col];
#pragma unroll
      for (int r = 0; r < 4; r++) {
        int row = m0 + wr + i * 16 + quad * 4 + r;
        float v = acc[i][j][r] + bcol;
        size_t idx = (size_t)row * Ndim + col;
        if (MODE == 0) {
          outb[idx] = f2bs(v);
        } else if (MODE == 1) {
          int orig = g_idx[row];
          outb[idx] = f2bs(v + resf[(size_t)orig * 256 + col]);
        } else if (MODE == 2) {
          float u = 0.7978845608028654f * (v + 0.044715f * v * v * v);
          float e = __expf(2.f * u);
          float th = 1.f - 2.f / (e + 1.f);
          outb[idx] = f2bs(0.5f * v * (1.f + th));
        } else {
          if (row < Mt) {
            int orig = g_idx[row];
            float o = (v + bf2f(resb[idx])) * wgt[orig];
            outf[(size_t)orig * 256 + col] = o;
          }
        }
      }
    }
  }
}

// ---------------- attention (compact, conflict-free V layout) ----------------
__global__ __launch_bounds__(256) void attn_k(
    const short* __restrict__ qkv, const float* __restrict__ amask,
    const int* __restrict__ g_idx, const int* __restrict__ startp,
    const int* __restrict__ cntp, short* __restrict__ ctx) {
  __shared__ __align__(16) short VF[2 * 12 * 64 * 8];
  __shared__ __align__(16) float ls[384];
  int bh = blockIdx.x >> 1, qhalf = blockIdx.x & 1;
  int bb = bh >> 3, h = bh & 7;
  int t = threadIdx.x;
  int start = startp[bb], cnt = cntp[bb];
  size_t base = (size_t)start * 768;
  for (int i = t; i < 1536; i += 256) {
    int k = i >> 2, cg = (i & 3) * 8;
    union { int4 v; short s[8]; } u;
    if (k < cnt) {
      u.v = *(const int4*)(qkv + base + (size_t)k * 768 + 512 + h * 32 + cg);
    } else {
      u.v = make_int4(0, 0, 0, 0);
    }
    int c = k >> 5, qd = (k >> 3) & 3, j = k & 7;
#pragma unroll
    for (int jj = 0; jj < 8; jj++) {
      int d = cg + jj;
      VF[((((d >> 4) * 12 + c) * 64) + qd * 16 + (d & 15)) * 8 + j] = u.s[jj];
    }
  }
  for (int i = t; i < 384; i += 256)
    ls[i] = (i < cnt) ? amask[g_idx[start + i]] : 0.f;
  __syncthreads();

  int wave = t >> 6, lane = t & 63;
  int ql = lane & 15, quad = lane >> 4;
  int addr0 = (((quad & 1) * 2) * 16 + ql) * 4;
  int addr1 = addr0 + 64;
  bool hiq = quad >= 2;
  int nt = (cnt + 15) >> 4;
  int nc = (cnt + 31) >> 5;

  for (int qt = qhalf + 2 * wave; qt < nt; qt += 8) {
    int q0 = qt * 16, qrow = q0 + ql;
    bf16x8 qf;
#pragma unroll
    for (int j = 0; j < 8; j++) qf[j] = 0;
    if (qrow < cnt)
      qf = *(const bf16x8*)(qkv + base + (size_t)qrow * 768 + h * 32 + quad * 8);

    f32x4 o0, o1;
#pragma unroll
    for (int r = 0; r < 4; r++) { o0[r] = 0.f; o1[r] = 0.f; }
    float lsum = 0.f;

    for (int c = 0; c < nc; c++) {
      int keyA = c * 32 + ql;
      int keyB = keyA + 16;
      bf16x8 kfA, kfB;
#pragma unroll
      for (int j = 0; j < 8; j++) { kfA[j] = 0; kfB[j] = 0; }
      if (keyA < cnt)
        kfA = *(const bf16x8*)(qkv + base + (size_t)keyA * 768 + 256 + h * 32 + quad * 8);
      if (keyB < cnt)
        kfB = *(const bf16x8*)(qkv + base + (size_t)keyB * 768 + 256 + h * 32 + quad * 8);
      f32x4 sa, sb;
#pragma unroll
      for (int r = 0; r < 4; r++) { sa[r] = 0.f; sb[r] = 0.f; }
      sa = __builtin_amdgcn_mfma_f32_16x16x32_bf16(kfA, qf, sa, 0, 0, 0);
      sb = __builtin_amdgcn_mfma_f32_16x16x32_bf16(kfB, qf, sb, 0, 0, 0);
      int kbase = c * 32 + quad * 4;
      float4 la = *(const float4*)&ls[kbase];
      float4 lb = *(const float4*)&ls[kbase + 16];
      float ea0 = (kbase + 0 < cnt) ? __expf(sa[0] * 0.17677669529663687f + la.x) : 0.f;
      float ea1 = (kbase + 1 < cnt) ? __expf(sa[1] * 0.17677669529663687f + la.y) : 0.f;
      float ea2 = (kbase + 2 < cnt) ? __expf(sa[2] * 0.17677669529663687f + la.z) : 0.f;
      float ea3 = (kbase + 3 < cnt) ? __expf(sa[3] * 0.17677669529663687f + la.w) : 0.f;
      float eb0 = (kbase + 16 < cnt) ? __expf(sb[0] * 0.17677669529663687f + lb.x) : 0.f;
      float eb1 = (kbase + 17 < cnt) ? __expf(sb[1] * 0.17677669529663687f + lb.y) : 0.f;
      float eb2 = (kbase + 18 < cnt) ? __expf(sb[2] * 0.17677669529663687f + lb.z) : 0.f;
      float eb3 = (kbase + 19 < cnt) ? __expf(sb[3] * 0.17677669529663687f + lb.w) : 0.f;
      lsum += (ea0 + ea1) + (ea2 + ea3) + (eb0 + eb1) + (eb2 + eb3);
      unsigned pA0 = packbf(ea0, ea1), pA1 = packbf(ea2, ea3);
      unsigned pB0 = packbf(eb0, eb1), pB1 = packbf(eb2, eb3);
      int s00 = __builtin_amdgcn_ds_bpermute(addr0, (int)pA0);
      int s10 = __builtin_amdgcn_ds_bpermute(addr0, (int)pB0);
      int s01 = __builtin_amdgcn_ds_bpermute(addr0, (int)pA1);
      int s11 = __builtin_amdgcn_ds_bpermute(addr0, (int)pB1);
      int s02 = __builtin_amdgcn_ds_bpermute(addr1, (int)pA0);
      int s12 = __builtin_amdgcn_ds_bpermute(addr1, (int)pB0);
      int s03 = __builtin_amdgcn_ds_bpermute(addr1, (int)pA1);
      int s13 = __builtin_amdgcn_ds_bpermute(addr1, (int)pB1);
      union { int i[4]; bf16x8 v; } pf;
      pf.i[0] = hiq ? s10 : s00;
      pf.i[1] = hiq ? s11 : s01;
      pf.i[2] = hiq ? s12 : s02;
      pf.i[3] = hiq ? s13 : s13;
      pf.i[3] = hiq ? s13 : s03;
      bf16x8 v0 = *(const bf16x8*)&VF[(c * 64 + lane) * 8];
      bf16x8 v1 = *(const bf16x8*)&VF[((12 + c) * 64 + lane) * 8];
      o0 = __builtin_amdgcn_mfma_f32_16x16x32_bf16(v0, pf.v, o0, 0, 0, 0);
      o1 = __builtin_amdgcn_mfma_f32_16x16x32_bf16(v1, pf.v, o1, 0, 0, 0);
    }
    lsum += __shfl_xor(lsum, 16);
    lsum += __shfl_xor(lsum, 32);
    float inv = 1.f / lsum;

    if (qrow < cnt) {
      size_t cb = ((size_t)(start + qrow)) * 256 + h * 32;
      uint2 w0, w1;
      w0.x = packbf(o0[0] * inv, o0[1] * inv);
      w0.y = packbf(o0[2] * inv, o0[3] * inv);
      w1.x = packbf(o1[0] * inv, o1[1] * inv);
      w1.y = packbf(o1[2] * inv, o1[3] * inv);
      *(uint2*)(ctx + cb + quad * 4) = w0;
      *(uint2*)(ctx + cb + 16 + quad * 4) = w1;
    }
  }
}

extern "C" void kernel_launch(void* const* d_in, const int* in_sizes, int n_in,
                              void* d_out, int out_size, void* d_ws,
                              size_t ws_size, hipStream_t stream) {
  const float* x = (const float*)d_in[0];
  const float* amask = (const float*)d_in[1];
  const float* wp_w = (const float*)d_in[2];
  const float* wp_b = (const float*)d_in[3];
  const float* a1_w = (const float*)d_in[4];
  const float* a1_b = (const float*)d_in[5];
  const float* a2_w = (const float*)d_in[6];
  const float* a2_b = (const float*)d_in[7];
  const float* ln1_g = (const float*)d_in[8];
  const float* ln1_b = (const float*)d_in[9];
  const float* wqkv = (const float*)d_in[10];
  const float* bqkv = (const float*)d_in[11];
  const float* wo = (const float*)d_in[12];
  const float* bo = (const float*)d_in[13];
  const float* ln2_g = (const float*)d_in[14];
  const float* ln2_b = (const float*)d_in[15];
  const float* w1 = (const float*)d_in[16];
  const float* b1 = (const float*)d_in[17];
  const float* w2 = (const float*)d_in[18];
  const float* b2 = (const float*)d_in[19];
  float* out = (float*)d_out;

  uint8_t* p = (uint8_t*)d_ws;
  float* weightsv = (float*)p; p += (size_t)TOKN * 4;
  int* selv = (int*)p;         p += (size_t)TOKN * 4;
  int* idxlv = (int*)p;        p += (size_t)TOKN * 4;
  int* gidxv = (int*)p;        p += (size_t)TOKN * 4;
  int* cntv = (int*)p;         p += 64 * 4;
  int* startv = (int*)p;       p += 64 * 4;
  int* mtotv = (int*)p;        p += 64 * 4;
  short* wqkvt = (short*)p;    p += (size_t)768 * 256 * 2;
  short* wot = (short*)p;      p += (size_t)256 * 256 * 2;
  short* w1t = (short*)p;      p += (size_t)1024 * 256 * 2;
  short* w2t = (short*)p;      p += (size_t)256 * 1024 * 2;
  short* h1bv = (short*)p;     p += (size_t)TOKN * 256 * 2;
  short* h2nv = (short*)p;     p += (size_t)TOKN * 256 * 2;
  short* ctxv = (short*)p;     p += (size_t)TOKN * 256 * 2;
  uint8_t* R = p;
  short* xnv = (short*)R;
  short* qkvv = (short*)(R + (size_t)TOKN * 256 * 2);
  short* actv = (short*)R;

  convw_k<<<dim3(1024), dim3(256), 0, stream>>>(wqkv, wo, w1, w2, wqkvt, wot, w1t, w2t);
  ln_router_k<<<dim3(TOKN / 4), dim3(256), 0, stream>>>(x, ln1_g, ln1_b, wp_w, wp_b,
                                                        xnv, weightsv, out);
  router_gemm_k<<<dim3(360), dim3(256), 0, stream>>>(x, a1_w, a1_b, a2_w, a2_b, selv);
  scanA_k<<<dim3(64), dim3(512), 0, stream>>>(selv, idxlv, cntv);
  scanB_k<<<dim3(1), dim3(512), 0, stream>>>(cntv, startv, mtotv, gidxv,
                                             out + (size_t)TOKN * 256);
  scanC_k<<<dim3(64), dim3(512), 0, stream>>>(idxlv, startv, cntv, gidxv);
  gemm_bt_k<0><<<dim3(6, 180), dim3(256), 0, stream>>>(
      xnv, wqkvt, bqkv, nullptr, nullptr, nullptr, gidxv, mtotv, qkvv, nullptr,
      768, 256);
  attn_k<<<dim3(1024), dim3(256), 0, stream>>>(qkvv, amask, gidxv, startv, cntv, ctxv);
  gemm_bt_k<1><<<dim3(2, 180), dim3(256), 0, stream>>>(
      ctxv, wot, bo, x, nullptr, nullptr, gidxv, mtotv, h1bv, nullptr, 256, 256);
  ln_k<<<dim3(TOKN / 4), dim3(256), 0, stream>>>(h1bv, ln2_g, ln2_b, mtotv, h2nv);
  gemm_bt_k<2><<<dim3(8, 180), dim3(256), 0, stream>>>(
      h2nv, w1t, b1, nullptr, nullptr, nullptr, gidxv, mtotv, actv, nullptr,
      1024, 256);
  gemm_bt_k<3><<<dim3(2, 180), dim3(256), 0, stream>>>(
      actv, w2t, b2, nullptr, h1bv, weightsv, gidxv, mtotv, nullptr, out, 256, 1024);
}

// Round 7
// 251.881 us; speedup vs baseline: 1.1153x; 1.1153x over previous
//
#include <hip/hip_runtime.h>
#include <math.h>
#include <stdint.h>

#define TOKN 23040
#define BSZ 64
#define SEQ 360
#define DIM 256
#define NHD 8
#define HDD 32
#define MLPD 1024
#define NEGV -1e9f

typedef __attribute__((ext_vector_type(8))) short bf16x8;
typedef __attribute__((ext_vector_type(4))) float f32x4;

static __device__ __forceinline__ short f2bs(float f) {
  unsigned u = __builtin_bit_cast(unsigned, f);
  u += 0x7fffu + ((u >> 16) & 1u);
  return (short)(u >> 16);
}
static __device__ __forceinline__ float bf2f(short s) {
  unsigned u = ((unsigned)(unsigned short)s) << 16;
  return __builtin_bit_cast(float, u);
}
static __device__ __forceinline__ unsigned packbf(float a, float b) {
  return (unsigned)(unsigned short)f2bs(a) | ((unsigned)(unsigned short)f2bs(b) << 16);
}
// async global->LDS, 16B/lane; LDS dest = wave-uniform base + lane*16
static __device__ __forceinline__ void gl16(const short* g, short* l) {
  __builtin_amdgcn_global_load_lds(
      (const __attribute__((address_space(1))) unsigned int*)g,
      (__attribute__((address_space(3))) unsigned int*)l, 16, 0, 0);
}

// ---------------- weight convert + transpose to bf16 [N][K] ----------------
__global__ __launch_bounds__(256) void convw_k(
    const float* __restrict__ wqkv, const float* __restrict__ wo,
    const float* __restrict__ w1, const float* __restrict__ w2,
    short* __restrict__ wqkvt, short* __restrict__ wot,
    short* __restrict__ w1t, short* __restrict__ w2t) {
  int id = blockIdx.x * 256 + threadIdx.x;
  if (id < 256 * 768) {
    int k = id / 768, n = id % 768;
    wqkvt[n * 256 + k] = f2bs(wqkv[id]);
  }
  if (id < 256 * 256) {
    int k = id >> 8, n = id & 255;
    wot[n * 256 + k] = f2bs(wo[id]);
  }
  if (id < 256 * 1024) {
    int k = id >> 10, n = id & 1023;
    w1t[n * 256 + k] = f2bs(w1[id]);
  }
  if (id < 1024 * 256) {
    int k = id >> 8, n = id & 255;
    w2t[n * 1024 + k] = f2bs(w2[id]);
  }
}

// ---------------- LN1 + router weight dot; 4 tokens/block ----------------
__global__ __launch_bounds__(256) void ln_router_k(
    const float* __restrict__ in, const float* __restrict__ g,
    const float* __restrict__ b, const float* __restrict__ wpw,
    const float* __restrict__ wpb, short* __restrict__ outn,
    float* __restrict__ wout, float* __restrict__ outx) {
  int tok = blockIdx.x * 4 + (threadIdx.x >> 6);
  int lane = threadIdx.x & 63;
  const float4 xv = *(const float4*)(in + (size_t)tok * DIM + lane * 4);
  *(float4*)(outx + (size_t)tok * DIM + lane * 4) = xv;  // passthrough default
  float s = xv.x + xv.y + xv.z + xv.w;
  float s2 = xv.x * xv.x + xv.y * xv.y + xv.z * xv.z + xv.w * xv.w;
#pragma unroll
  for (int o = 1; o < 64; o <<= 1) { s += __shfl_xor(s, o); s2 += __shfl_xor(s2, o); }
  float m = s * (1.f / DIM);
  float var = fmaxf(s2 * (1.f / DIM) - m * m, 0.f);
  float rstd = rsqrtf(var + 1e-5f);
  float4 gv = *(const float4*)(g + lane * 4);
  float4 bv = *(const float4*)(b + lane * 4);
  uint2 pk;
  pk.x = packbf((xv.x - m) * rstd * gv.x + bv.x, (xv.y - m) * rstd * gv.y + bv.y);
  pk.y = packbf((xv.z - m) * rstd * gv.z + bv.z, (xv.w - m) * rstd * gv.w + bv.w);
  *(uint2*)(outn + (size_t)tok * DIM + lane * 4) = pk;
  float4 wv = *(const float4*)(wpw + lane * 4);
  float wd = xv.x * wv.x + xv.y * wv.y + xv.z * wv.z + xv.w * wv.w;
#pragma unroll
  for (int o = 1; o < 64; o <<= 1) wd += __shfl_xor(wd, o);
  if (lane == 0) wout[tok] = wd + wpb[0];
}

// ---------------- LN2 compact; bf16 in -> bf16 out, wave early-exit ----------------
__global__ __launch_bounds__(256) void ln_k(
    const short* __restrict__ in, const float* __restrict__ g,
    const float* __restrict__ b, const int* __restrict__ mtotp,
    short* __restrict__ outn) {
  int tok = blockIdx.x * 4 + (threadIdx.x >> 6);
  int lane = threadIdx.x & 63;
  if (tok >= *mtotp) return;  // wave-uniform, no barriers in kernel
  union { uint2 v; short s[4]; } u;
  u.v = *(const uint2*)(in + (size_t)tok * DIM + lane * 4);
  float x0 = bf2f(u.s[0]), x1 = bf2f(u.s[1]), x2 = bf2f(u.s[2]), x3 = bf2f(u.s[3]);
  float s = x0 + x1 + x2 + x3;
  float s2 = x0 * x0 + x1 * x1 + x2 * x2 + x3 * x3;
#pragma unroll
  for (int o = 1; o < 64; o <<= 1) { s += __shfl_xor(s, o); s2 += __shfl_xor(s2, o); }
  float m = s * (1.f / DIM);
  float var = fmaxf(s2 * (1.f / DIM) - m * m, 0.f);
  float rstd = rsqrtf(var + 1e-5f);
  float4 gv = *(const float4*)(g + lane * 4);
  float4 bv = *(const float4*)(b + lane * 4);
  uint2 pk;
  pk.x = packbf((x0 - m) * rstd * gv.x + bv.x, (x1 - m) * rstd * gv.y + bv.y);
  pk.y = packbf((x2 - m) * rstd * gv.z + bv.z, (x3 - m) * rstd * gv.w + bv.w);
  *(uint2*)(outn + (size_t)tok * DIM + lane * 4) = pk;
}

// ---------------- router fused: a1 GEMM (fp32) + silu + a2 + argmax -> sel ----------------
__global__ __launch_bounds__(256) void router_gemm_k(
    const float* __restrict__ x, const float* __restrict__ a1w,
    const float* __restrict__ a1b, const float* __restrict__ a2w,
    const float* __restrict__ a2b, int* __restrict__ sel) {
  __shared__ __align__(16) float XT[32][65];
  __shared__ __align__(16) float WT[32][128];
  int m0 = blockIdx.x * 64;
  int t = threadIdx.x;
  int tx = t & 31, ty = t >> 5;
  float acc[8][4] = {};
  int r = t >> 2, c = (t & 3) * 8;
  int n2 = t >> 1, c2 = (t & 1) * 16;
  for (int k0 = 0; k0 < 256; k0 += 32) {
    float4 xa = *(const float4*)(x + (size_t)(m0 + r) * 256 + k0 + c);
    float4 xb = *(const float4*)(x + (size_t)(m0 + r) * 256 + k0 + c + 4);
    XT[c + 0][r] = xa.x; XT[c + 1][r] = xa.y; XT[c + 2][r] = xa.z; XT[c + 3][r] = xa.w;
    XT[c + 4][r] = xb.x; XT[c + 5][r] = xb.y; XT[c + 6][r] = xb.z; XT[c + 7][r] = xb.w;
#pragma unroll
    for (int j = 0; j < 4; j++) {
      float4 wv = *(const float4*)(a1w + (size_t)n2 * 256 + k0 + c2 + j * 4);
      WT[c2 + j * 4 + 0][n2] = wv.x;
      WT[c2 + j * 4 + 1][n2] = wv.y;
      WT[c2 + j * 4 + 2][n2] = wv.z;
      WT[c2 + j * 4 + 3][n2] = wv.w;
    }
    __syncthreads();
#pragma unroll 8
    for (int kk = 0; kk < 32; kk++) {
      float4 wv4 = *(const float4*)&WT[kk][tx * 4];
      float4 x0 = *(const float4*)&XT[kk][ty * 8];
      float4 x1 = *(const float4*)&XT[kk][ty * 8 + 4];
      float xr[8] = {x0.x, x0.y, x0.z, x0.w, x1.x, x1.y, x1.z, x1.w};
      float wr[4] = {wv4.x, wv4.y, wv4.z, wv4.w};
#pragma unroll
      for (int i = 0; i < 8; i++)
#pragma unroll
        for (int j = 0; j < 4; j++) acc[i][j] += xr[i] * wr[j];
    }
    __syncthreads();
  }
  float b1v[4], a20[4], a21[4];
#pragma unroll
  for (int j = 0; j < 4; j++) {
    int dim = tx * 4 + j;
    b1v[j] = a1b[dim];
    a20[j] = a2w[dim];
    a21[j] = a2w[128 + dim];
  }
  float bias0 = a2b[0], bias1 = a2b[1];
#pragma unroll
  for (int i = 0; i < 8; i++) {
    float l0 = 0.f, l1 = 0.f;
#pragma unroll
    for (int j = 0; j < 4; j++) {
      float v = acc[i][j] + b1v[j];
      float h = v / (1.f + expf(-v));
      l0 += h * a20[j];
      l1 += h * a21[j];
    }
#pragma unroll
    for (int o = 1; o < 32; o <<= 1) { l0 += __shfl_xor(l0, o); l1 += __shfl_xor(l1, o); }
    if (tx == 0) sel[m0 + ty * 8 + i] = (l1 + bias1 > l0 + bias0) ? 1 : 0;
  }
}

// ---------------- compaction ----------------
__global__ __launch_bounds__(512) void scanA_k(const int* __restrict__ sel,
                                               int* __restrict__ idxl,
                                               int* __restrict__ cnt) {
  __shared__ int sc[512];
  int b = blockIdx.x, t = threadIdx.x;
  int flag = (t < SEQ) ? sel[b * SEQ + t] : 0;
  sc[t] = flag;
  __syncthreads();
  int val = flag;
  for (int off = 1; off < 512; off <<= 1) {
    int add = (t >= off) ? sc[t - off] : 0;
    __syncthreads();
    val += add;
    sc[t] = val;
    __syncthreads();
  }
  if (flag) idxl[b * SEQ + (val - 1)] = t;
  if (t == 511) cnt[b] = val;
}

__global__ __launch_bounds__(512) void scanB_k(const int* __restrict__ cnt,
                                               int* __restrict__ startp,
                                               int* __restrict__ mtotp,
                                               int* __restrict__ g_idx,
                                               float* __restrict__ outavg) {
  __shared__ int sc[64];
  __shared__ int mt;
  int t = threadIdx.x;
  if (t < 64) sc[t] = cnt[t];
  __syncthreads();
  if (t == 0) {
    int run = 0;
    for (int b = 0; b < 64; b++) { startp[b] = run; run += sc[b]; }
    *mtotp = run;
    mt = run;
    outavg[0] = (float)run / 64.0f;  // avg_selected fused
  }
  __syncthreads();
  int m = mt;
  for (int i = m + t; i < TOKN; i += 512) g_idx[i] = 0;  // pad rows -> token 0
}

__global__ __launch_bounds__(512) void scanC_k(const int* __restrict__ idxl,
                                               const int* __restrict__ startp,
                                               const int* __restrict__ cnt,
                                               int* __restrict__ g_idx) {
  int b = blockIdx.x, t = threadIdx.x;
  int c = cnt[b], s0 = startp[b];
  for (int j = t; j < c; j += 512) g_idx[s0 + j] = b * SEQ + idxl[b * SEQ + j];
}

// ---------------- bf16 MFMA GEMM: 64x64 tile, BK=64 (4x 64x32 LDS bufs) ----------------
// Staging via global_load_lds width-16: each 64x32 buffer = one block-wide
// issue (lane-linear LDS mapping). Per wave per barrier pair: 8 MFMAs +
// 8 ds_read_b128. Grid stays large (>=720 blocks) -> blocks/CU >= 3, so
// inter-block wave overlap hides the barrier drain (the R6 128-tile failed
// exactly here: 180 blocks, 6% occupancy).
// MODE 0: A gathered via g_idx; outb = bf16(v)                     (qkv)
// MODE 1: outb = bf16(v + resf[g_idx[row]])                        (h1, bf16)
// MODE 2: outb = bf16(gelu(v))                                     (mlp act)
// MODE 3: out[g_idx[row]] = (v + bf2f(resb[row]))*wgt[g_idx[row]]  (scatter)
template <int MODE>
__global__ __launch_bounds__(256) void gemm_bt_k(
    const short* __restrict__ A, const short* __restrict__ Bt,
    const float* __restrict__ bias, const float* __restrict__ resf,
    const short* __restrict__ resb, const float* __restrict__ wgt,
    const int* __restrict__ g_idx, const int* __restrict__ mtotp,
    short* __restrict__ outb, float* __restrict__ outf, int Ndim, int Kdim) {
  int Mt = *mtotp;
  int m0 = blockIdx.y * 64;
  if (m0 >= Mt) return;
  __shared__ __align__(16) short As0[64 * 32];
  __shared__ __align__(16) short As1[64 * 32];
  __shared__ __align__(16) short Bs0[64 * 32];
  __shared__ __align__(16) short Bs1[64 * 32];
  int n0 = blockIdx.x * 64;
  int t = threadIdx.x;
  int wave = t >> 6, lane = t & 63;
  int l15 = lane & 15, quad = lane >> 4;
  int wr = (wave >> 1) * 32, wc = (wave & 1) * 32;
  // staging: row = t>>2 (0..63), colgroup = (t&3)*8 within each buffer
  int r0 = t >> 2, c0 = (t & 3) * 8;
  long ar0 = (MODE == 0) ? g_idx[m0 + r0] : (m0 + r0);
  const short* gA = A + ar0 * Kdim + c0;
  const short* gB = Bt + (size_t)(n0 + r0) * Kdim + c0;
  short* lA0 = As0 + wave * 512;  // wave-uniform base; HW adds lane*16B
  short* lA1 = As1 + wave * 512;
  short* lB0 = Bs0 + wave * 512;
  short* lB1 = Bs1 + wave * 512;

  f32x4 acc[2][2];
#pragma unroll
  for (int i = 0; i < 2; i++)
#pragma unroll
    for (int j = 0; j < 2; j++)
#pragma unroll
      for (int r = 0; r < 4; r++) acc[i][j][r] = 0.f;

  for (int k0 = 0; k0 < Kdim; k0 += 64) {
    gl16(gA + k0, lA0);
    gl16(gA + k0 + 32, lA1);
    gl16(gB + k0, lB0);
    gl16(gB + k0 + 32, lB1);
    __syncthreads();
    bf16x8 a0[2], a1[2], b0[2], b1[2];
#pragma unroll
    for (int i = 0; i < 2; i++) {
      a0[i] = *(const bf16x8*)&As0[(wr + i * 16 + l15) * 32 + quad * 8];
      a1[i] = *(const bf16x8*)&As1[(wr + i * 16 + l15) * 32 + quad * 8];
      b0[i] = *(const bf16x8*)&Bs0[(wc + i * 16 + l15) * 32 + quad * 8];
      b1[i] = *(const bf16x8*)&Bs1[(wc + i * 16 + l15) * 32 + quad * 8];
    }
#pragma unroll
    for (int i = 0; i < 2; i++)
#pragma unroll
      for (int j = 0; j < 2; j++) {
        acc[i][j] = __builtin_amdgcn_mfma_f32_16x16x32_bf16(a0[i], b0[j],
                                                            acc[i][j], 0, 0, 0);
        acc[i][j] = __builtin_amdgcn_mfma_f32_16x16x32_bf16(a1[i], b1[j],
                                                            acc[i][j], 0, 0, 0);
      }
    __syncthreads();
  }

#pragma unroll
  for (int i = 0; i < 2; i++) {
#pragma unroll
    for (int j = 0; j < 2; j++) {
      int col = n0 + wc + j * 16 + l15;
      float bcol = bias[col];
#pragma unroll
      for (int r = 0; r < 4; r++) {
        int row = m0 + wr + i * 16 + quad * 4 + r;
        float v = acc[i][j][r] + bcol;
        size_t idx = (size_t)row * Ndim + col;
        if (MODE == 0) {
          outb[idx] = f2bs(v);
        } else if (MODE == 1) {
          int orig = g_idx[row];
          outb[idx] = f2bs(v + resf[(size_t)orig * 256 + col]);
        } else if (MODE == 2) {
          float u = 0.7978845608028654f * (v + 0.044715f * v * v * v);
          float e = __expf(2.f * u);
          float th = 1.f - 2.f / (e + 1.f);
          outb[idx] = f2bs(0.5f * v * (1.f + th));
        } else {
          if (row < Mt) {
            int orig = g_idx[row];
            float o = (v + bf2f(resb[idx])) * wgt[orig];
            outf[(size_t)orig * 256 + col] = o;
          }
        }
      }
    }
  }
}

// ---------------- attention (compact, conflict-free V layout) ----------------
__global__ __launch_bounds__(256) void attn_k(
    const short* __restrict__ qkv, const float* __restrict__ amask,
    const int* __restrict__ g_idx, const int* __restrict__ startp,
    const int* __restrict__ cntp, short* __restrict__ ctx) {
  __shared__ __align__(16) short VF[2 * 12 * 64 * 8];
  __shared__ __align__(16) float ls[384];
  int bh = blockIdx.x >> 1, qhalf = blockIdx.x & 1;
  int bb = bh >> 3, h = bh & 7;
  int t = threadIdx.x;
  int start = startp[bb], cnt = cntp[bb];
  size_t base = (size_t)start * 768;
  for (int i = t; i < 1536; i += 256) {
    int k = i >> 2, cg = (i & 3) * 8;
    union { int4 v; short s[8]; } u;
    if (k < cnt) {
      u.v = *(const int4*)(qkv + base + (size_t)k * 768 + 512 + h * 32 + cg);
    } else {
      u.v = make_int4(0, 0, 0, 0);
    }
    int c = k >> 5, qd = (k >> 3) & 3, j = k & 7;
#pragma unroll
    for (int jj = 0; jj < 8; jj++) {
      int d = cg + jj;
      VF[((((d >> 4) * 12 + c) * 64) + qd * 16 + (d & 15)) * 8 + j] = u.s[jj];
    }
  }
  for (int i = t; i < 384; i += 256)
    ls[i] = (i < cnt) ? amask[g_idx[start + i]] : 0.f;
  __syncthreads();

  int wave = t >> 6, lane = t & 63;
  int ql = lane & 15, quad = lane >> 4;
  int addr0 = (((quad & 1) * 2) * 16 + ql) * 4;
  int addr1 = addr0 + 64;
  bool hiq = quad >= 2;
  int nt = (cnt + 15) >> 4;
  int nc = (cnt + 31) >> 5;

  for (int qt = qhalf + 2 * wave; qt < nt; qt += 8) {
    int q0 = qt * 16, qrow = q0 + ql;
    bf16x8 qf;
#pragma unroll
    for (int j = 0; j < 8; j++) qf[j] = 0;
    if (qrow < cnt)
      qf = *(const bf16x8*)(qkv + base + (size_t)qrow * 768 + h * 32 + quad * 8);

    f32x4 o0, o1;
#pragma unroll
    for (int r = 0; r < 4; r++) { o0[r] = 0.f; o1[r] = 0.f; }
    float lsum = 0.f;

    for (int c = 0; c < nc; c++) {
      int keyA = c * 32 + ql;
      int keyB = keyA + 16;
      bf16x8 kfA, kfB;
#pragma unroll
      for (int j = 0; j < 8; j++) { kfA[j] = 0; kfB[j] = 0; }
      if (keyA < cnt)
        kfA = *(const bf16x8*)(qkv + base + (size_t)keyA * 768 + 256 + h * 32 + quad * 8);
      if (keyB < cnt)
        kfB = *(const bf16x8*)(qkv + base + (size_t)keyB * 768 + 256 + h * 32 + quad * 8);
      f32x4 sa, sb;
#pragma unroll
      for (int r = 0; r < 4; r++) { sa[r] = 0.f; sb[r] = 0.f; }
      sa = __builtin_amdgcn_mfma_f32_16x16x32_bf16(kfA, qf, sa, 0, 0, 0);
      sb = __builtin_amdgcn_mfma_f32_16x16x32_bf16(kfB, qf, sb, 0, 0, 0);
      int kbase = c * 32 + quad * 4;
      float4 la = *(const float4*)&ls[kbase];
      float4 lb = *(const float4*)&ls[kbase + 16];
      float ea0 = (kbase + 0 < cnt) ? __expf(sa[0] * 0.17677669529663687f + la.x) : 0.f;
      float ea1 = (kbase + 1 < cnt) ? __expf(sa[1] * 0.17677669529663687f + la.y) : 0.f;
      float ea2 = (kbase + 2 < cnt) ? __expf(sa[2] * 0.17677669529663687f + la.z) : 0.f;
      float ea3 = (kbase + 3 < cnt) ? __expf(sa[3] * 0.17677669529663687f + la.w) : 0.f;
      float eb0 = (kbase + 16 < cnt) ? __expf(sb[0] * 0.17677669529663687f + lb.x) : 0.f;
      float eb1 = (kbase + 17 < cnt) ? __expf(sb[1] * 0.17677669529663687f + lb.y) : 0.f;
      float eb2 = (kbase + 18 < cnt) ? __expf(sb[2] * 0.17677669529663687f + lb.z) : 0.f;
      float eb3 = (kbase + 19 < cnt) ? __expf(sb[3] * 0.17677669529663687f + lb.w) : 0.f;
      lsum += (ea0 + ea1) + (ea2 + ea3) + (eb0 + eb1) + (eb2 + eb3);
      unsigned pA0 = packbf(ea0, ea1), pA1 = packbf(ea2, ea3);
      unsigned pB0 = packbf(eb0, eb1), pB1 = packbf(eb2, eb3);
      int s00 = __builtin_amdgcn_ds_bpermute(addr0, (int)pA0);
      int s10 = __builtin_amdgcn_ds_bpermute(addr0, (int)pB0);
      int s01 = __builtin_amdgcn_ds_bpermute(addr0, (int)pA1);
      int s11 = __builtin_amdgcn_ds_bpermute(addr0, (int)pB1);
      int s02 = __builtin_amdgcn_ds_bpermute(addr1, (int)pA0);
      int s12 = __builtin_amdgcn_ds_bpermute(addr1, (int)pB0);
      int s03 = __builtin_amdgcn_ds_bpermute(addr1, (int)pA1);
      int s13 = __builtin_amdgcn_ds_bpermute(addr1, (int)pB1);
      union { int i[4]; bf16x8 v; } pf;
      pf.i[0] = hiq ? s10 : s00;
      pf.i[1] = hiq ? s11 : s01;
      pf.i[2] = hiq ? s12 : s02;
      pf.i[3] = hiq ? s13 : s03;
      bf16x8 v0 = *(const bf16x8*)&VF[(c * 64 + lane) * 8];
      bf16x8 v1 = *(const bf16x8*)&VF[((12 + c) * 64 + lane) * 8];
      o0 = __builtin_amdgcn_mfma_f32_16x16x32_bf16(v0, pf.v, o0, 0, 0, 0);
      o1 = __builtin_amdgcn_mfma_f32_16x16x32_bf16(v1, pf.v, o1, 0, 0, 0);
    }
    lsum += __shfl_xor(lsum, 16);
    lsum += __shfl_xor(lsum, 32);
    float inv = 1.f / lsum;

    if (qrow < cnt) {
      size_t cb = ((size_t)(start + qrow)) * 256 + h * 32;
      uint2 w0, w1;
      w0.x = packbf(o0[0] * inv, o0[1] * inv);
      w0.y = packbf(o0[2] * inv, o0[3] * inv);
      w1.x = packbf(o1[0] * inv, o1[1] * inv);
      w1.y = packbf(o1[2] * inv, o1[3] * inv);
      *(uint2*)(ctx + cb + quad * 4) = w0;
      *(uint2*)(ctx + cb + 16 + quad * 4) = w1;
    }
  }
}

extern "C" void kernel_launch(void* const* d_in, const int* in_sizes, int n_in,
                              void* d_out, int out_size, void* d_ws,
                              size_t ws_size, hipStream_t stream) {
  const float* x = (const float*)d_in[0];
  const float* amask = (const float*)d_in[1];
  const float* wp_w = (const float*)d_in[2];
  const float* wp_b = (const float*)d_in[3];
  const float* a1_w = (const float*)d_in[4];
  const float* a1_b = (const float*)d_in[5];
  const float* a2_w = (const float*)d_in[6];
  const float* a2_b = (const float*)d_in[7];
  const float* ln1_g = (const float*)d_in[8];
  const float* ln1_b = (const float*)d_in[9];
  const float* wqkv = (const float*)d_in[10];
  const float* bqkv = (const float*)d_in[11];
  const float* wo = (const float*)d_in[12];
  const float* bo = (const float*)d_in[13];
  const float* ln2_g = (const float*)d_in[14];
  const float* ln2_b = (const float*)d_in[15];
  const float* w1 = (const float*)d_in[16];
  const float* b1 = (const float*)d_in[17];
  const float* w2 = (const float*)d_in[18];
  const float* b2 = (const float*)d_in[19];
  float* out = (float*)d_out;

  uint8_t* p = (uint8_t*)d_ws;
  float* weightsv = (float*)p; p += (size_t)TOKN * 4;
  int* selv = (int*)p;         p += (size_t)TOKN * 4;
  int* idxlv = (int*)p;        p += (size_t)TOKN * 4;
  int* gidxv = (int*)p;        p += (size_t)TOKN * 4;
  int* cntv = (int*)p;         p += 64 * 4;
  int* startv = (int*)p;       p += 64 * 4;
  int* mtotv = (int*)p;        p += 64 * 4;
  short* wqkvt = (short*)p;    p += (size_t)768 * 256 * 2;
  short* wot = (short*)p;      p += (size_t)256 * 256 * 2;
  short* w1t = (short*)p;      p += (size_t)1024 * 256 * 2;
  short* w2t = (short*)p;      p += (size_t)256 * 1024 * 2;
  short* h1bv = (short*)p;     p += (size_t)TOKN * 256 * 2;
  short* h2nv = (short*)p;     p += (size_t)TOKN * 256 * 2;
  short* ctxv = (short*)p;     p += (size_t)TOKN * 256 * 2;
  uint8_t* R = p;
  short* xnv = (short*)R;
  short* qkvv = (short*)(R + (size_t)TOKN * 256 * 2);
  short* actv = (short*)R;

  convw_k<<<dim3(1024), dim3(256), 0, stream>>>(wqkv, wo, w1, w2, wqkvt, wot, w1t, w2t);
  ln_router_k<<<dim3(TOKN / 4), dim3(256), 0, stream>>>(x, ln1_g, ln1_b, wp_w, wp_b,
                                                        xnv, weightsv, out);
  router_gemm_k<<<dim3(360), dim3(256), 0, stream>>>(x, a1_w, a1_b, a2_w, a2_b, selv);
  scanA_k<<<dim3(64), dim3(512), 0, stream>>>(selv, idxlv, cntv);
  scanB_k<<<dim3(1), dim3(512), 0, stream>>>(cntv, startv, mtotv, gidxv,
                                             out + (size_t)TOKN * 256);
  scanC_k<<<dim3(64), dim3(512), 0, stream>>>(idxlv, startv, cntv, gidxv);
  gemm_bt_k<0><<<dim3(12, 360), dim3(256), 0, stream>>>(
      xnv, wqkvt, bqkv, nullptr, nullptr, nullptr, gidxv, mtotv, qkvv, nullptr,
      768, 256);
  attn_k<<<dim3(1024), dim3(256), 0, stream>>>(qkvv, amask, gidxv, startv, cntv, ctxv);
  gemm_bt_k<1><<<dim3(4, 360), dim3(256), 0, stream>>>(
      ctxv, wot, bo, x, nullptr, nullptr, gidxv, mtotv, h1bv, nullptr, 256, 256);
  ln_k<<<dim3(TOKN / 4), dim3(256), 0, stream>>>(h1bv, ln2_g, ln2_b, mtotv, h2nv);
  gemm_bt_k<2><<<dim3(16, 360), dim3(256), 0, stream>>>(
      h2nv, w1t, b1, nullptr, nullptr, nullptr, gidxv, mtotv, actv, nullptr,
      1024, 256);
  gemm_bt_k<3><<<dim3(4, 360), dim3(256), 0, stream>>>(
      actv, w2t, b2, nullptr, h1bv, weightsv, gidxv, mtotv, nullptr, out, 256, 1024);
}

// Round 8
// 245.785 us; speedup vs baseline: 1.1430x; 1.0248x over previous
//
#include <hip/hip_runtime.h>
#include <math.h>
#include <stdint.h>

#define TOKN 23040
#define BSZ 64
#define SEQ 360
#define DIM 256
#define NHD 8
#define HDD 32
#define MLPD 1024
#define NEGV -1e9f

typedef __attribute__((ext_vector_type(8))) short bf16x8;
typedef __attribute__((ext_vector_type(4))) float f32x4;

static __device__ __forceinline__ short f2bs(float f) {
  unsigned u = __builtin_bit_cast(unsigned, f);
  u += 0x7fffu + ((u >> 16) & 1u);
  return (short)(u >> 16);
}
static __device__ __forceinline__ float bf2f(short s) {
  unsigned u = ((unsigned)(unsigned short)s) << 16;
  return __builtin_bit_cast(float, u);
}
static __device__ __forceinline__ unsigned packbf(float a, float b) {
  return (unsigned)(unsigned short)f2bs(a) | ((unsigned)(unsigned short)f2bs(b) << 16);
}
// async global->LDS, 16B/lane; LDS dest = wave-uniform base + lane*16
static __device__ __forceinline__ void gl16(const short* g, short* l) {
  __builtin_amdgcn_global_load_lds(
      (const __attribute__((address_space(1))) unsigned int*)g,
      (__attribute__((address_space(3))) unsigned int*)l, 16, 0, 0);
}

// ---------------- weight convert + transpose to bf16 [N][K] ----------------
__global__ __launch_bounds__(256) void convw_k(
    const float* __restrict__ wqkv, const float* __restrict__ wo,
    const float* __restrict__ w1, const float* __restrict__ w2,
    short* __restrict__ wqkvt, short* __restrict__ wot,
    short* __restrict__ w1t, short* __restrict__ w2t) {
  int id = blockIdx.x * 256 + threadIdx.x;
  if (id < 256 * 768) {
    int k = id / 768, n = id % 768;
    wqkvt[n * 256 + k] = f2bs(wqkv[id]);
  }
  if (id < 256 * 256) {
    int k = id >> 8, n = id & 255;
    wot[n * 256 + k] = f2bs(wo[id]);
  }
  if (id < 256 * 1024) {
    int k = id >> 10, n = id & 1023;
    w1t[n * 256 + k] = f2bs(w1[id]);
  }
  if (id < 1024 * 256) {
    int k = id >> 8, n = id & 255;
    w2t[n * 1024 + k] = f2bs(w2[id]);
  }
}

// ---------------- LN1 + router weight dot; 4 tokens/block ----------------
__global__ __launch_bounds__(256) void ln_router_k(
    const float* __restrict__ in, const float* __restrict__ g,
    const float* __restrict__ b, const float* __restrict__ wpw,
    const float* __restrict__ wpb, short* __restrict__ outn,
    float* __restrict__ wout, float* __restrict__ outx) {
  int tok = blockIdx.x * 4 + (threadIdx.x >> 6);
  int lane = threadIdx.x & 63;
  const float4 xv = *(const float4*)(in + (size_t)tok * DIM + lane * 4);
  *(float4*)(outx + (size_t)tok * DIM + lane * 4) = xv;  // passthrough default
  float s = xv.x + xv.y + xv.z + xv.w;
  float s2 = xv.x * xv.x + xv.y * xv.y + xv.z * xv.z + xv.w * xv.w;
#pragma unroll
  for (int o = 1; o < 64; o <<= 1) { s += __shfl_xor(s, o); s2 += __shfl_xor(s2, o); }
  float m = s * (1.f / DIM);
  float var = fmaxf(s2 * (1.f / DIM) - m * m, 0.f);
  float rstd = rsqrtf(var + 1e-5f);
  float4 gv = *(const float4*)(g + lane * 4);
  float4 bv = *(const float4*)(b + lane * 4);
  uint2 pk;
  pk.x = packbf((xv.x - m) * rstd * gv.x + bv.x, (xv.y - m) * rstd * gv.y + bv.y);
  pk.y = packbf((xv.z - m) * rstd * gv.z + bv.z, (xv.w - m) * rstd * gv.w + bv.w);
  *(uint2*)(outn + (size_t)tok * DIM + lane * 4) = pk;
  float4 wv = *(const float4*)(wpw + lane * 4);
  float wd = xv.x * wv.x + xv.y * wv.y + xv.z * wv.z + xv.w * wv.w;
#pragma unroll
  for (int o = 1; o < 64; o <<= 1) wd += __shfl_xor(wd, o);
  if (lane == 0) wout[tok] = wd + wpb[0];
}

// ---------------- LN2 compact; bf16 in -> bf16 out, wave early-exit ----------------
__global__ __launch_bounds__(256) void ln_k(
    const short* __restrict__ in, const float* __restrict__ g,
    const float* __restrict__ b, const int* __restrict__ mtotp,
    short* __restrict__ outn) {
  int tok = blockIdx.x * 4 + (threadIdx.x >> 6);
  int lane = threadIdx.x & 63;
  if (tok >= *mtotp) return;  // wave-uniform, no barriers in kernel
  union { uint2 v; short s[4]; } u;
  u.v = *(const uint2*)(in + (size_t)tok * DIM + lane * 4);
  float x0 = bf2f(u.s[0]), x1 = bf2f(u.s[1]), x2 = bf2f(u.s[2]), x3 = bf2f(u.s[3]);
  float s = x0 + x1 + x2 + x3;
  float s2 = x0 * x0 + x1 * x1 + x2 * x2 + x3 * x3;
#pragma unroll
  for (int o = 1; o < 64; o <<= 1) { s += __shfl_xor(s, o); s2 += __shfl_xor(s2, o); }
  float m = s * (1.f / DIM);
  float var = fmaxf(s2 * (1.f / DIM) - m * m, 0.f);
  float rstd = rsqrtf(var + 1e-5f);
  float4 gv = *(const float4*)(g + lane * 4);
  float4 bv = *(const float4*)(b + lane * 4);
  uint2 pk;
  pk.x = packbf((x0 - m) * rstd * gv.x + bv.x, (x1 - m) * rstd * gv.y + bv.y);
  pk.y = packbf((x2 - m) * rstd * gv.z + bv.z, (x3 - m) * rstd * gv.w + bv.w);
  *(uint2*)(outn + (size_t)tok * DIM + lane * 4) = pk;
}

// ---------------- router fused: a1 GEMM (fp32) + silu + a2 + argmax -> sel ----------------
// M=32 tile -> 720 blocks (~11 waves/CU; the R5 M=64 version was grid-starved
// at 360 blocks / 11% occupancy and stuck at 42us). Per kk: 2 ds_read_b128 +
// 16 FMA. XT padded to 36 so &XT[kk][ty*4] stays 16B-aligned.
__global__ __launch_bounds__(256) void router_gemm_k(
    const float* __restrict__ x, const float* __restrict__ a1w,
    const float* __restrict__ a1b, const float* __restrict__ a2w,
    const float* __restrict__ a2b, int* __restrict__ sel) {
  __shared__ __align__(16) float XT[32][36];
  __shared__ __align__(16) float WT[32][128];
  int m0 = blockIdx.x * 32;
  int t = threadIdx.x;
  int tx = t & 31, ty = t >> 5;  // tx: 4-dim group, ty: 4-token group
  float acc[4][4] = {};
  int r = t >> 3, c = (t & 7) * 4;    // X staging: token r, k-cols c..c+3
  int n2 = t >> 1, c2 = (t & 1) * 16; // W staging: dim n2, k-cols c2..c2+15
  for (int k0 = 0; k0 < 256; k0 += 32) {
    float4 xa = *(const float4*)(x + (size_t)(m0 + r) * 256 + k0 + c);
    XT[c + 0][r] = xa.x; XT[c + 1][r] = xa.y; XT[c + 2][r] = xa.z; XT[c + 3][r] = xa.w;
#pragma unroll
    for (int j = 0; j < 4; j++) {
      float4 wv = *(const float4*)(a1w + (size_t)n2 * 256 + k0 + c2 + j * 4);
      WT[c2 + j * 4 + 0][n2] = wv.x;
      WT[c2 + j * 4 + 1][n2] = wv.y;
      WT[c2 + j * 4 + 2][n2] = wv.z;
      WT[c2 + j * 4 + 3][n2] = wv.w;
    }
    __syncthreads();
#pragma unroll 8
    for (int kk = 0; kk < 32; kk++) {
      float4 wv4 = *(const float4*)&WT[kk][tx * 4];
      float4 xv4 = *(const float4*)&XT[kk][ty * 4];
      float xr[4] = {xv4.x, xv4.y, xv4.z, xv4.w};
      float wr[4] = {wv4.x, wv4.y, wv4.z, wv4.w};
#pragma unroll
      for (int i = 0; i < 4; i++)
#pragma unroll
        for (int j = 0; j < 4; j++) acc[i][j] += xr[i] * wr[j];
    }
    __syncthreads();
  }
  float b1v[4], a20[4], a21[4];
#pragma unroll
  for (int j = 0; j < 4; j++) {
    int dim = tx * 4 + j;
    b1v[j] = a1b[dim];
    a20[j] = a2w[dim];
    a21[j] = a2w[128 + dim];
  }
  float bias0 = a2b[0], bias1 = a2b[1];
#pragma unroll
  for (int i = 0; i < 4; i++) {
    float l0 = 0.f, l1 = 0.f;
#pragma unroll
    for (int j = 0; j < 4; j++) {
      float v = acc[i][j] + b1v[j];
      float h = v / (1.f + expf(-v));
      l0 += h * a20[j];
      l1 += h * a21[j];
    }
#pragma unroll
    for (int o = 1; o < 32; o <<= 1) { l0 += __shfl_xor(l0, o); l1 += __shfl_xor(l1, o); }
    if (tx == 0) sel[m0 + ty * 4 + i] = (l1 + bias1 > l0 + bias0) ? 1 : 0;
  }
}

// ---------------- compaction ----------------
__global__ __launch_bounds__(512) void scanA_k(const int* __restrict__ sel,
                                               int* __restrict__ idxl,
                                               int* __restrict__ cnt) {
  __shared__ int sc[512];
  int b = blockIdx.x, t = threadIdx.x;
  int flag = (t < SEQ) ? sel[b * SEQ + t] : 0;
  sc[t] = flag;
  __syncthreads();
  int val = flag;
  for (int off = 1; off < 512; off <<= 1) {
    int add = (t >= off) ? sc[t - off] : 0;
    __syncthreads();
    val += add;
    sc[t] = val;
    __syncthreads();
  }
  if (flag) idxl[b * SEQ + (val - 1)] = t;
  if (t == 511) cnt[b] = val;
}

__global__ __launch_bounds__(512) void scanB_k(const int* __restrict__ cnt,
                                               int* __restrict__ startp,
                                               int* __restrict__ mtotp,
                                               int* __restrict__ g_idx,
                                               float* __restrict__ outavg) {
  __shared__ int sc[64];
  __shared__ int mt;
  int t = threadIdx.x;
  if (t < 64) sc[t] = cnt[t];
  __syncthreads();
  if (t == 0) {
    int run = 0;
    for (int b = 0; b < 64; b++) { startp[b] = run; run += sc[b]; }
    *mtotp = run;
    mt = run;
    outavg[0] = (float)run / 64.0f;  // avg_selected fused
  }
  __syncthreads();
  int m = mt;
  for (int i = m + t; i < TOKN; i += 512) g_idx[i] = 0;  // pad rows -> token 0
}

__global__ __launch_bounds__(512) void scanC_k(const int* __restrict__ idxl,
                                               const int* __restrict__ startp,
                                               const int* __restrict__ cnt,
                                               int* __restrict__ g_idx) {
  int b = blockIdx.x, t = threadIdx.x;
  int c = cnt[b], s0 = startp[b];
  for (int j = t; j < c; j += 512) g_idx[s0 + j] = b * SEQ + idxl[b * SEQ + j];
}

// ---------------- bf16 MFMA GEMM: 64x64 tile, BK=64 (4x 64x32 LDS bufs) ----------------
template <int MODE>
__global__ __launch_bounds__(256) void gemm_bt_k(
    const short* __restrict__ A, const short* __restrict__ Bt,
    const float* __restrict__ bias, const float* __restrict__ resf,
    const short* __restrict__ resb, const float* __restrict__ wgt,
    const int* __restrict__ g_idx, const int* __restrict__ mtotp,
    short* __restrict__ outb, float* __restrict__ outf, int Ndim, int Kdim) {
  int Mt = *mtotp;
  int m0 = blockIdx.y * 64;
  if (m0 >= Mt) return;
  __shared__ __align__(16) short As0[64 * 32];
  __shared__ __align__(16) short As1[64 * 32];
  __shared__ __align__(16) short Bs0[64 * 32];
  __shared__ __align__(16) short Bs1[64 * 32];
  int n0 = blockIdx.x * 64;
  int t = threadIdx.x;
  int wave = t >> 6, lane = t & 63;
  int l15 = lane & 15, quad = lane >> 4;
  int wr = (wave >> 1) * 32, wc = (wave & 1) * 32;
  int r0 = t >> 2, c0 = (t & 3) * 8;
  long ar0 = (MODE == 0) ? g_idx[m0 + r0] : (m0 + r0);
  const short* gA = A + ar0 * Kdim + c0;
  const short* gB = Bt + (size_t)(n0 + r0) * Kdim + c0;
  short* lA0 = As0 + wave * 512;  // wave-uniform base; HW adds lane*16B
  short* lA1 = As1 + wave * 512;
  short* lB0 = Bs0 + wave * 512;
  short* lB1 = Bs1 + wave * 512;

  f32x4 acc[2][2];
#pragma unroll
  for (int i = 0; i < 2; i++)
#pragma unroll
    for (int j = 0; j < 2; j++)
#pragma unroll
      for (int r = 0; r < 4; r++) acc[i][j][r] = 0.f;

  for (int k0 = 0; k0 < Kdim; k0 += 64) {
    gl16(gA + k0, lA0);
    gl16(gA + k0 + 32, lA1);
    gl16(gB + k0, lB0);
    gl16(gB + k0 + 32, lB1);
    __syncthreads();
    bf16x8 a0[2], a1[2], b0[2], b1[2];
#pragma unroll
    for (int i = 0; i < 2; i++) {
      a0[i] = *(const bf16x8*)&As0[(wr + i * 16 + l15) * 32 + quad * 8];
      a1[i] = *(const bf16x8*)&As1[(wr + i * 16 + l15) * 32 + quad * 8];
      b0[i] = *(const bf16x8*)&Bs0[(wc + i * 16 + l15) * 32 + quad * 8];
      b1[i] = *(const bf16x8*)&Bs1[(wc + i * 16 + l15) * 32 + quad * 8];
    }
#pragma unroll
    for (int i = 0; i < 2; i++)
#pragma unroll
      for (int j = 0; j < 2; j++) {
        acc[i][j] = __builtin_amdgcn_mfma_f32_16x16x32_bf16(a0[i], b0[j],
                                                            acc[i][j], 0, 0, 0);
        acc[i][j] = __builtin_amdgcn_mfma_f32_16x16x32_bf16(a1[i], b1[j],
                                                            acc[i][j], 0, 0, 0);
      }
    __syncthreads();
  }

#pragma unroll
  for (int i = 0; i < 2; i++) {
#pragma unroll
    for (int j = 0; j < 2; j++) {
      int col = n0 + wc + j * 16 + l15;
      float bcol = bias[col];
#pragma unroll
      for (int r = 0; r < 4; r++) {
        int row = m0 + wr + i * 16 + quad * 4 + r;
        float v = acc[i][j][r] + bcol;
        size_t idx = (size_t)row * Ndim + col;
        if (MODE == 0) {
          outb[idx] = f2bs(v);
        } else if (MODE == 1) {
          int orig = g_idx[row];
          outb[idx] = f2bs(v + resf[(size_t)orig * 256 + col]);
        } else if (MODE == 2) {
          float u = 0.7978845608028654f * (v + 0.044715f * v * v * v);
          float e = __expf(2.f * u);
          float th = 1.f - 2.f / (e + 1.f);
          outb[idx] = f2bs(0.5f * v * (1.f + th));
        } else {
          if (row < Mt) {
            int orig = g_idx[row];
            float o = (v + bf2f(resb[idx])) * wgt[orig];
            outf[(size_t)orig * 256 + col] = o;
          }
        }
      }
    }
  }
}

// ---------------- attention (compact, conflict-free V layout) ----------------
__global__ __launch_bounds__(256) void attn_k(
    const short* __restrict__ qkv, const float* __restrict__ amask,
    const int* __restrict__ g_idx, const int* __restrict__ startp,
    const int* __restrict__ cntp, short* __restrict__ ctx) {
  __shared__ __align__(16) short VF[2 * 12 * 64 * 8];
  __shared__ __align__(16) float ls[384];
  int bh = blockIdx.x >> 1, qhalf = blockIdx.x & 1;
  int bb = bh >> 3, h = bh & 7;
  int t = threadIdx.x;
  int start = startp[bb], cnt = cntp[bb];
  size_t base = (size_t)start * 768;
  for (int i = t; i < 1536; i += 256) {
    int k = i >> 2, cg = (i & 3) * 8;
    union { int4 v; short s[8]; } u;
    if (k < cnt) {
      u.v = *(const int4*)(qkv + base + (size_t)k * 768 + 512 + h * 32 + cg);
    } else {
      u.v = make_int4(0, 0, 0, 0);
    }
    int c = k >> 5, qd = (k >> 3) & 3, j = k & 7;
#pragma unroll
    for (int jj = 0; jj < 8; jj++) {
      int d = cg + jj;
      VF[((((d >> 4) * 12 + c) * 64) + qd * 16 + (d & 15)) * 8 + j] = u.s[jj];
    }
  }
  for (int i = t; i < 384; i += 256)
    ls[i] = (i < cnt) ? amask[g_idx[start + i]] : 0.f;
  __syncthreads();

  int wave = t >> 6, lane = t & 63;
  int ql = lane & 15, quad = lane >> 4;
  int addr0 = (((quad & 1) * 2) * 16 + ql) * 4;
  int addr1 = addr0 + 64;
  bool hiq = quad >= 2;
  int nt = (cnt + 15) >> 4;
  int nc = (cnt + 31) >> 5;

  for (int qt = qhalf + 2 * wave; qt < nt; qt += 8) {
    int q0 = qt * 16, qrow = q0 + ql;
    bf16x8 qf;
#pragma unroll
    for (int j = 0; j < 8; j++) qf[j] = 0;
    if (qrow < cnt)
      qf = *(const bf16x8*)(qkv + base + (size_t)qrow * 768 + h * 32 + quad * 8);

    f32x4 o0, o1;
#pragma unroll
    for (int r = 0; r < 4; r++) { o0[r] = 0.f; o1[r] = 0.f; }
    float lsum = 0.f;

    for (int c = 0; c < nc; c++) {
      int keyA = c * 32 + ql;
      int keyB = keyA + 16;
      bf16x8 kfA, kfB;
#pragma unroll
      for (int j = 0; j < 8; j++) { kfA[j] = 0; kfB[j] = 0; }
      if (keyA < cnt)
        kfA = *(const bf16x8*)(qkv + base + (size_t)keyA * 768 + 256 + h * 32 + quad * 8);
      if (keyB < cnt)
        kfB = *(const bf16x8*)(qkv + base + (size_t)keyB * 768 + 256 + h * 32 + quad * 8);
      f32x4 sa, sb;
#pragma unroll
      for (int r = 0; r < 4; r++) { sa[r] = 0.f; sb[r] = 0.f; }
      sa = __builtin_amdgcn_mfma_f32_16x16x32_bf16(kfA, qf, sa, 0, 0, 0);
      sb = __builtin_amdgcn_mfma_f32_16x16x32_bf16(kfB, qf, sb, 0, 0, 0);
      int kbase = c * 32 + quad * 4;
      float4 la = *(const float4*)&ls[kbase];
      float4 lb = *(const float4*)&ls[kbase + 16];
      float ea0 = (kbase + 0 < cnt) ? __expf(sa[0] * 0.17677669529663687f + la.x) : 0.f;
      float ea1 = (kbase + 1 < cnt) ? __expf(sa[1] * 0.17677669529663687f + la.y) : 0.f;
      float ea2 = (kbase + 2 < cnt) ? __expf(sa[2] * 0.17677669529663687f + la.z) : 0.f;
      float ea3 = (kbase + 3 < cnt) ? __expf(sa[3] * 0.17677669529663687f + la.w) : 0.f;
      float eb0 = (kbase + 16 < cnt) ? __expf(sb[0] * 0.17677669529663687f + lb.x) : 0.f;
      float eb1 = (kbase + 17 < cnt) ? __expf(sb[1] * 0.17677669529663687f + lb.y) : 0.f;
      float eb2 = (kbase + 18 < cnt) ? __expf(sb[2] * 0.17677669529663687f + lb.z) : 0.f;
      float eb3 = (kbase + 19 < cnt) ? __expf(sb[3] * 0.17677669529663687f + lb.w) : 0.f;
      lsum += (ea0 + ea1) + (ea2 + ea3) + (eb0 + eb1) + (eb2 + eb3);
      unsigned pA0 = packbf(ea0, ea1), pA1 = packbf(ea2, ea3);
      unsigned pB0 = packbf(eb0, eb1), pB1 = packbf(eb2, eb3);
      int s00 = __builtin_amdgcn_ds_bpermute(addr0, (int)pA0);
      int s10 = __builtin_amdgcn_ds_bpermute(addr0, (int)pB0);
      int s01 = __builtin_amdgcn_ds_bpermute(addr0, (int)pA1);
      int s11 = __builtin_amdgcn_ds_bpermute(addr0, (int)pB1);
      int s02 = __builtin_amdgcn_ds_bpermute(addr1, (int)pA0);
      int s12 = __builtin_amdgcn_ds_bpermute(addr1, (int)pB0);
      int s03 = __builtin_amdgcn_ds_bpermute(addr1, (int)pA1);
      int s13 = __builtin_amdgcn_ds_bpermute(addr1, (int)pB1);
      union { int i[4]; bf16x8 v; } pf;
      pf.i[0] = hiq ? s10 : s00;
      pf.i[1] = hiq ? s11 : s01;
      pf.i[2] = hiq ? s12 : s02;
      pf.i[3] = hiq ? s13 : s03;
      bf16x8 v0 = *(const bf16x8*)&VF[(c * 64 + lane) * 8];
      bf16x8 v1 = *(const bf16x8*)&VF[((12 + c) * 64 + lane) * 8];
      o0 = __builtin_amdgcn_mfma_f32_16x16x32_bf16(v0, pf.v, o0, 0, 0, 0);
      o1 = __builtin_amdgcn_mfma_f32_16x16x32_bf16(v1, pf.v, o1, 0, 0, 0);
    }
    lsum += __shfl_xor(lsum, 16);
    lsum += __shfl_xor(lsum, 32);
    float inv = 1.f / lsum;

    if (qrow < cnt) {
      size_t cb = ((size_t)(start + qrow)) * 256 + h * 32;
      uint2 w0, w1;
      w0.x = packbf(o0[0] * inv, o0[1] * inv);
      w0.y = packbf(o0[2] * inv, o0[3] * inv);
      w1.x = packbf(o1[0] * inv, o1[1] * inv);
      w1.y = packbf(o1[2] * inv, o1[3] * inv);
      *(uint2*)(ctx + cb + quad * 4) = w0;
      *(uint2*)(ctx + cb + 16 + quad * 4) = w1;
    }
  }
}

extern "C" void kernel_launch(void* const* d_in, const int* in_sizes, int n_in,
                              void* d_out, int out_size, void* d_ws,
                              size_t ws_size, hipStream_t stream) {
  const float* x = (const float*)d_in[0];
  const float* amask = (const float*)d_in[1];
  const float* wp_w = (const float*)d_in[2];
  const float* wp_b = (const float*)d_in[3];
  const float* a1_w = (const float*)d_in[4];
  const float* a1_b = (const float*)d_in[5];
  const float* a2_w = (const float*)d_in[6];
  const float* a2_b = (const float*)d_in[7];
  const float* ln1_g = (const float*)d_in[8];
  const float* ln1_b = (const float*)d_in[9];
  const float* wqkv = (const float*)d_in[10];
  const float* bqkv = (const float*)d_in[11];
  const float* wo = (const float*)d_in[12];
  const float* bo = (const float*)d_in[13];
  const float* ln2_g = (const float*)d_in[14];
  const float* ln2_b = (const float*)d_in[15];
  const float* w1 = (const float*)d_in[16];
  const float* b1 = (const float*)d_in[17];
  const float* w2 = (const float*)d_in[18];
  const float* b2 = (const float*)d_in[19];
  float* out = (float*)d_out;

  uint8_t* p = (uint8_t*)d_ws;
  float* weightsv = (float*)p; p += (size_t)TOKN * 4;
  int* selv = (int*)p;         p += (size_t)TOKN * 4;
  int* idxlv = (int*)p;        p += (size_t)TOKN * 4;
  int* gidxv = (int*)p;        p += (size_t)TOKN * 4;
  int* cntv = (int*)p;         p += 64 * 4;
  int* startv = (int*)p;       p += 64 * 4;
  int* mtotv = (int*)p;        p += 64 * 4;
  short* wqkvt = (short*)p;    p += (size_t)768 * 256 * 2;
  short* wot = (short*)p;      p += (size_t)256 * 256 * 2;
  short* w1t = (short*)p;      p += (size_t)1024 * 256 * 2;
  short* w2t = (short*)p;      p += (size_t)256 * 1024 * 2;
  short* h1bv = (short*)p;     p += (size_t)TOKN * 256 * 2;
  short* h2nv = (short*)p;     p += (size_t)TOKN * 256 * 2;
  short* ctxv = (short*)p;     p += (size_t)TOKN * 256 * 2;
  uint8_t* R = p;
  short* xnv = (short*)R;
  short* qkvv = (short*)(R + (size_t)TOKN * 256 * 2);
  short* actv = (short*)R;

  convw_k<<<dim3(1024), dim3(256), 0, stream>>>(wqkv, wo, w1, w2, wqkvt, wot, w1t, w2t);
  ln_router_k<<<dim3(TOKN / 4), dim3(256), 0, stream>>>(x, ln1_g, ln1_b, wp_w, wp_b,
                                                        xnv, weightsv, out);
  router_gemm_k<<<dim3(720), dim3(256), 0, stream>>>(x, a1_w, a1_b, a2_w, a2_b, selv);
  scanA_k<<<dim3(64), dim3(512), 0, stream>>>(selv, idxlv, cntv);
  scanB_k<<<dim3(1), dim3(512), 0, stream>>>(cntv, startv, mtotv, gidxv,
                                             out + (size_t)TOKN * 256);
  scanC_k<<<dim3(64), dim3(512), 0, stream>>>(idxlv, startv, cntv, gidxv);
  gemm_bt_k<0><<<dim3(12, 360), dim3(256), 0, stream>>>(
      xnv, wqkvt, bqkv, nullptr, nullptr, nullptr, gidxv, mtotv, qkvv, nullptr,
      768, 256);
  attn_k<<<dim3(1024), dim3(256), 0, stream>>>(qkvv, amask, gidxv, startv, cntv, ctxv);
  gemm_bt_k<1><<<dim3(4, 360), dim3(256), 0, stream>>>(
      ctxv, wot, bo, x, nullptr, nullptr, gidxv, mtotv, h1bv, nullptr, 256, 256);
  ln_k<<<dim3(TOKN / 4), dim3(256), 0, stream>>>(h1bv, ln2_g, ln2_b, mtotv, h2nv);
  gemm_bt_k<2><<<dim3(16, 360), dim3(256), 0, stream>>>(
      h2nv, w1t, b1, nullptr, nullptr, nullptr, gidxv, mtotv, actv, nullptr,
      1024, 256);
  gemm_bt_k<3><<<dim3(4, 360), dim3(256), 0, stream>>>(
      actv, w2t, b2, nullptr, h1bv, weightsv, gidxv, mtotv, nullptr, out, 256, 1024);
}